// Round 7
// baseline (100.248 us; speedup 1.0000x reference)
//
#include <hip/hip_runtime.h>
#include <hip/hip_bf16.h>

static constexpr int Nc = 256;
static constexpr float NEGc = -1e30f;
static constexpr float SLOPEc = 0.01f;

using f32x4 = __attribute__((ext_vector_type(4))) float;
using s16x8 = __attribute__((ext_vector_type(8))) short;
typedef unsigned int u32;
typedef __attribute__((address_space(1))) const u32 gu32;
typedef __attribute__((address_space(3))) u32 lu32;

__device__ __forceinline__ void mfma16(f32x4& d, s16x8 a, s16x8 b) {
    // D = A(16x32)*B(32x16)+D ; A row=lane&15,k=(lane>>4)*8+reg ; B col=lane&15
    // C/D col=lane&15, row=(lane>>4)*4+reg   (validated rounds 1-6)
    asm("v_mfma_f32_16x16x32_bf16 %0, %1, %2, %0" : "+v"(d) : "v"(a), "v"(b));
}

// async global->LDS, 16B per lane; LDS dest = wave-uniform base + lane*16
__device__ __forceinline__ void gload16(ushort* lds, const void* g) {
    __builtin_amdgcn_global_load_lds((gu32*)(unsigned long long)g,
                                     (lu32*)(unsigned long long)lds, 16, 0, 0);
}

__device__ __forceinline__ float wredMax(float v) {
#pragma unroll
    for (int o = 32; o; o >>= 1) v = fmaxf(v, __shfl_xor(v, o, 64));
    return v;
}
__device__ __forceinline__ float wredSum(float v) {
#pragma unroll
    for (int o = 32; o; o >>= 1) v += __shfl_xor(v, o, 64);
    return v;
}

__device__ __forceinline__ unsigned packhi(unsigned u1, unsigned u0) {
    return __builtin_amdgcn_perm(u1, u0, 0x07060302u);
}

// ---------------------------------------------------------------------------
// convert_all: fused split weights F = [ W | W@Wa | W@Wb ] ([chunk][448][8]
// hi/lo), fused 448-wide biases, AND feature pre-split into slab layout
// [slab 64][kchunk 96][64 rows][8].
// items: [0,43520) W-split, [43520,182784) WA, [182784,183680) bias,
//        [183680,576896) X-split
// ---------------------------------------------------------------------------
__global__ void __launch_bounds__(256) convert_all(
    const float* __restrict__ W0, const float* __restrict__ b0,
    const float* __restrict__ W1, const float* __restrict__ b1,
    const float* __restrict__ A1, const float* __restrict__ ab1,
    const float* __restrict__ feat,
    ushort* __restrict__ F0h, ushort* __restrict__ F0l,
    ushort* __restrict__ F1h, ushort* __restrict__ F1l,
    float* __restrict__ bias0, float* __restrict__ bias1,
    ushort* __restrict__ Xh, ushort* __restrict__ Xl) {
    int idx = blockIdx.x * 256 + threadIdx.x;
    if (idx >= 576896) return;

    if (idx < 43520) {
        // W-split: [0,30720) W0, [30720,43520) W1
        const float* src; ushort *dh, *dl; int K, ch, c;
        if (idx < 30720) { src = W0; dh = F0h; dl = F0l; K = 768;
                           ch = idx / 320; c = idx - ch * 320; }
        else { int off = idx - 30720; src = W1; dh = F1h; dl = F1l; K = 300;
               ch = off / 320; c = off - ch * 320; }
        float v[8];
#pragma unroll
        for (int e = 0; e < 8; e++) {
            int k = ch * 8 + e;
            v[e] = (k < K && c < 300) ? src[(size_t)k * 300 + c] : 0.f;
        }
        unsigned hu[4], lu[4];
#pragma unroll
        for (int q = 0; q < 4; q++) {
            unsigned u0 = __float_as_uint(v[q * 2]);
            unsigned u1 = __float_as_uint(v[q * 2 + 1]);
            float r0 = v[q * 2] - __uint_as_float(u0 & 0xFFFF0000u);
            float r1 = v[q * 2 + 1] - __uint_as_float(u1 & 0xFFFF0000u);
            hu[q] = packhi(u1, u0);
            lu[q] = packhi(__float_as_uint(r1), __float_as_uint(r0));
        }
        size_t dst = ((size_t)ch * 448 + c) * 8;
        *(uint4*)&dh[dst] = make_uint4(hu[0], hu[1], hu[2], hu[3]);
        *(uint4*)&dl[dst] = make_uint4(lu[0], lu[1], lu[2], lu[3]);
    } else if (idx < 182784) {
        // WA: one 300-MAC dot per thread
        const float* Wsrc; ushort *dh, *dl; int K, idx2;
        if (idx < 141824) { idx2 = idx - 43520; Wsrc = W0; dh = F0h; dl = F0l; K = 768; }
        else { idx2 = idx - 141824; Wsrc = W1; dh = F1h; dl = F1l; K = 300; }
        int k = idx2 >> 7, c = idx2 & 127;
        float accv = 0.f;
        if (k < K) {
            const float* wrow = Wsrc + (size_t)k * 300;
            const float* a1c = (c < 64) ? (A1 + c) : (A1 + 300 * 64 + (c - 64));
            for (int mm = 0; mm < 300; mm += 4) {
                accv += wrow[mm] * a1c[(size_t)mm * 64]
                      + wrow[mm + 1] * a1c[(size_t)(mm + 1) * 64]
                      + wrow[mm + 2] * a1c[(size_t)(mm + 2) * 64]
                      + wrow[mm + 3] * a1c[(size_t)(mm + 3) * 64];
            }
        }
        unsigned u = __float_as_uint(accv);
        float r = accv - __uint_as_float(u & 0xFFFF0000u);
        size_t dst = ((size_t)(k >> 3) * 448 + 320 + c) * 8 + (k & 7);
        dh[dst] = (ushort)(u >> 16);
        dl[dst] = (ushort)(__float_as_uint(r) >> 16);
    } else if (idx < 183680) {
        // bias fold
        int off = idx - 182784;
        int layer = off / 448, col = off - layer * 448;
        const float* b = layer ? b1 : b0;
        float v;
        if (col < 320) {
            v = (col < 300) ? b[col] : 0.f;
        } else {
            int cc = col - 320;
            const float* a1c = (cc < 64) ? (A1 + cc) : (A1 + 300 * 64 + (cc - 64));
            float s = 0.f;
            for (int mm = 0; mm < 300; mm++) s += b[mm] * a1c[(size_t)mm * 64];
            v = s + ((cc >= 64) ? ab1[cc - 64] : 0.f);
        }
        (layer ? bias1 : bias0)[col] = v;
    } else {
        // X-split: slab layout [s][ch][64][8]
        int off = idx - 183680;
        int s = off / 6144, rem = off - s * 6144;
        int r = rem / 96, ch = rem - r * 96;
        const float* src = feat + ((size_t)(s * 64 + r)) * 768 + ch * 8;
        float v[8];
        *(float4*)&v[0] = *(const float4*)(src);
        *(float4*)&v[4] = *(const float4*)(src + 4);
        unsigned hu[4], lu[4];
#pragma unroll
        for (int q = 0; q < 4; q++) {
            unsigned u0 = __float_as_uint(v[q * 2]);
            unsigned u1 = __float_as_uint(v[q * 2 + 1]);
            float r0 = v[q * 2] - __uint_as_float(u0 & 0xFFFF0000u);
            float r1 = v[q * 2 + 1] - __uint_as_float(u1 & 0xFFFF0000u);
            hu[q] = packhi(u1, u0);
            lu[q] = packhi(__float_as_uint(r1), __float_as_uint(r0));
        }
        size_t dst = ((size_t)s * 96 + ch) * 512 + r * 8;
        *(uint4*)&Xh[dst] = make_uint4(hu[0], hu[1], hu[2], hu[3]);
        *(uint4*)&Xl[dst] = make_uint4(lu[0], lu[1], lu[2], lu[3]);
    }
}

// ---------------------------------------------------------------------------
// Async GEMM core: 64x64 tile, split-bf16 3-pass MFMA, all operands pre-split
// in global (slab layouts). Staging = pure global_load_lds (16B), double
// buffered, ONE barrier per K-step; next-tile loads overlap ds_read+MFMA.
// smem layout (ushort): buf*8192 + {Ah:0, Al:2048, Bh:4096, Bl:6144}
// ---------------------------------------------------------------------------
__device__ __forceinline__ void gemm_core_async(
    ushort* smem,
    const char* __restrict__ AhB, const char* __restrict__ AlB,
    const char* __restrict__ BhB, const char* __restrict__ BlB,
    int WCOLS, int col0, int Kp, f32x4 (&acc)[2][2]) {
    const int tid = threadIdx.x;
    const int lane = tid & 63, wave = tid >> 6;
    const int wm = wave >> 1, wn = wave & 1;
    const int m = lane & 15, kch = lane >> 4;

    auto issue = [&](int k0, int buf) {
        size_t ao = (size_t)k0 * 128 + wave * 1024 + lane * 16;
        gload16(smem + buf * 8192 + wave * 512, AhB + ao);
        gload16(smem + buf * 8192 + 2048 + wave * 512, AlB + ao);
        size_t bo = ((size_t)((k0 >> 3) + wave) * WCOLS + col0 + lane) * 16;
        gload16(smem + buf * 8192 + 4096 + wave * 512, BhB + bo);
        gload16(smem + buf * 8192 + 6144 + wave * 512, BlB + bo);
    };

    issue(0, 0);
    __syncthreads();   // vmcnt(0) drained at barrier
    for (int k0 = 0; k0 < Kp; k0 += 32) {
        const int cur = (k0 >> 5) & 1;
        if (k0 + 32 < Kp) issue(k0 + 32, cur ^ 1);   // overlaps reads+MFMA
        s16x8 Afh[2], Afl[2], Bfh[2], Bfl[2];
#pragma unroll
        for (int fr = 0; fr < 2; fr++) {
            int off = cur * 8192 + (kch * 64 + wm * 32 + fr * 16 + m) * 8;
            Afh[fr] = *(const s16x8*)&smem[off];
            Afl[fr] = *(const s16x8*)&smem[off + 2048];
        }
#pragma unroll
        for (int fc = 0; fc < 2; fc++) {
            int off = cur * 8192 + 4096 + (kch * 64 + wn * 32 + fc * 16 + m) * 8;
            Bfh[fc] = *(const s16x8*)&smem[off];
            Bfl[fc] = *(const s16x8*)&smem[off + 2048];
        }
#pragma unroll
        for (int fr = 0; fr < 2; fr++)
#pragma unroll
            for (int fc = 0; fc < 2; fc++) {
                mfma16(acc[fr][fc], Afh[fr], Bfh[fc]);
                mfma16(acc[fr][fc], Afl[fr], Bfh[fc]);
                mfma16(acc[fr][fc], Afh[fr], Bfl[fc]);
            }
        __syncthreads();
    }
}

// ---------------------------------------------------------------------------
// xf: [ h-split | si | sjT ] = X @ F + bias   (448 cols); A pre-split slabs
// ---------------------------------------------------------------------------
__global__ void __launch_bounds__(256) xf_kernel(
    const ushort* __restrict__ Xh, const ushort* __restrict__ Xl, int Kp,
    const ushort* __restrict__ Fh, const ushort* __restrict__ Fl,
    const float* __restrict__ bias,
    ushort* __restrict__ Hh, ushort* __restrict__ Hl,
    float* __restrict__ si, float* __restrict__ sjT) {
    __shared__ __align__(16) ushort smem[16384];
    const int tid = threadIdx.x;
    const int lane = tid & 63, wave = tid >> 6;
    const int wm = wave >> 1, wn = wave & 1;
    const int m = lane & 15, kch = lane >> 4;
    const int row0 = blockIdx.y * 64, col0 = blockIdx.x * 64;

    f32x4 acc[2][2];
#pragma unroll
    for (int i = 0; i < 2; i++)
#pragma unroll
        for (int j = 0; j < 2; j++)
#pragma unroll
            for (int e = 0; e < 4; e++) acc[i][j][e] = 0.f;

    const size_t slabOff = (size_t)blockIdx.y * Kp * 64;   // shorts
    gemm_core_async(smem, (const char*)(Xh + slabOff), (const char*)(Xl + slabOff),
                    (const char*)Fh, (const char*)Fl, 448, col0, Kp, acc);
    asm volatile("s_nop 7\ns_nop 7\ns_nop 7" ::);

#pragma unroll
    for (int fr = 0; fr < 2; fr++) {
        int rbase = row0 + wm * 32 + fr * 16 + (kch << 2);
#pragma unroll
        for (int fc = 0; fc < 2; fc++) {
            int col = col0 + wn * 32 + fc * 16 + m;
            float bv = bias[col];
            float vv[4];
#pragma unroll
            for (int e = 0; e < 4; e++) vv[e] = acc[fr][fc][e] + bv;
            if (col < 320) {           // h -> hi/lo split, H layout
                unsigned u0 = __float_as_uint(vv[0]);
                unsigned u1 = __float_as_uint(vv[1]);
                unsigned u2 = __float_as_uint(vv[2]);
                unsigned u3 = __float_as_uint(vv[3]);
                float r0 = vv[0] - __uint_as_float(u0 & 0xFFFF0000u);
                float r1 = vv[1] - __uint_as_float(u1 & 0xFFFF0000u);
                float r2 = vv[2] - __uint_as_float(u2 & 0xFFFF0000u);
                float r3 = vv[3] - __uint_as_float(u3 & 0xFFFF0000u);
                uint2 th, tl;
                th.x = packhi(u1, u0); th.y = packhi(u3, u2);
                tl.x = packhi(__float_as_uint(r1), __float_as_uint(r0));
                tl.y = packhi(__float_as_uint(r3), __float_as_uint(r2));
                int k = rbase & 255, bb = rbase >> 8;
                size_t dst = (size_t)bb * 81920 + ((size_t)(k >> 3) * 320 + col) * 8 + (k & 7);
                *(uint2*)&Hh[dst] = th;
                *(uint2*)&Hl[dst] = tl;
            } else if (col < 384) {    // si fp32
                int cc = col - 320;
#pragma unroll
                for (int e = 0; e < 4; e++)
                    si[(size_t)(rbase + e) * 64 + cc] = vv[e];
            } else {                   // sjT fp32 (transposed, coalesced)
                int cc = col - 384;
                int bb = rbase >> 8, j0 = rbase & 255;
                float4 v4 = make_float4(vv[0], vv[1], vv[2], vv[3]);
                *(float4*)&sjT[((size_t)(bb * 64 + cc)) * Nc + j0] = v4;
            }
        }
    }
}

// ---------------------------------------------------------------------------
// scores: e = leaky(a2 . relu(si+sj)), mask, per-row max/sum-exp,
// P = exp(e-rowmax) written SPLIT bf16 in PV slab layout [slab][kc][64][8].
// ---------------------------------------------------------------------------
__global__ void __launch_bounds__(256) scores_kernel(
    const float* __restrict__ si, const float* __restrict__ sjT,
    const float* __restrict__ adj, const float* __restrict__ A2,
    const float* __restrict__ ab2p,
    ushort* __restrict__ Ph, ushort* __restrict__ Pl,
    float* __restrict__ rmx, float* __restrict__ rsm) {
    int b = blockIdx.x, ic = blockIdx.y;
    const int j = threadIdx.x;
    __shared__ __align__(16) float sis[8][68];
    __shared__ __align__(16) float a2s[64];
    __shared__ __align__(16) float E[8][260];

    if (j < 64) a2s[j] = A2[j];
#pragma unroll
    for (int idx = j, t = 0; t < 2; t++, idx += 256) {
        int r = idx >> 6, h = idx & 63;
        sis[r][h] = si[(size_t)(b * Nc + ic * 8 + r) * 64 + h];
    }
    float sv[64];
    const float* sjb = sjT + ((size_t)b << 6) * Nc + j;
#pragma unroll
    for (int h = 0; h < 64; h++) sv[h] = sjb[(size_t)h * Nc];
    __syncthreads();

    float acc[8] = {};
#pragma unroll
    for (int hq = 0; hq < 16; hq++) {
        float4 a2q = *(const float4*)&a2s[hq * 4];
#pragma unroll
        for (int r = 0; r < 8; r++) {
            const float4 siq = *(const float4*)&sis[r][hq * 4];
            acc[r] += a2q.x * fmaxf(siq.x + sv[hq * 4 + 0], 0.f)
                    + a2q.y * fmaxf(siq.y + sv[hq * 4 + 1], 0.f)
                    + a2q.z * fmaxf(siq.z + sv[hq * 4 + 2], 0.f)
                    + a2q.w * fmaxf(siq.w + sv[hq * 4 + 3], 0.f);
        }
    }
    float ab2v = ab2p[0];
    const float* adjp = adj + (size_t)(b * Nc + ic * 8) * Nc + j;
#pragma unroll
    for (int r = 0; r < 8; r++) {
        float e = acc[r] + ab2v;
        e = e > 0.f ? e : SLOPEc * e;
        float a = adjp[(size_t)r * Nc];
        E[r][j] = (a != 0.f) ? e : NEGc;
    }
    __syncthreads();
    int wv = j >> 6, lane = j & 63;
#pragma unroll
    for (int rr = 0; rr < 2; rr++) {
        int r = wv * 2 + rr;
        float4 q = *(const float4*)&E[r][lane * 4];
        float m4 = fmaxf(fmaxf(q.x, q.y), fmaxf(q.z, q.w));
        float rm = wredMax(m4);
        float4 p;
        p.x = expf(q.x - rm); p.y = expf(q.y - rm);
        p.z = expf(q.z - rm); p.w = expf(q.w - rm);
        float rs = wredSum(p.x + p.y + p.z + p.w);
        int gi = ic * 8 + r;
        // split write, PV slab layout
        unsigned u0 = __float_as_uint(p.x), u1 = __float_as_uint(p.y);
        unsigned u2 = __float_as_uint(p.z), u3 = __float_as_uint(p.w);
        float r0 = p.x - __uint_as_float(u0 & 0xFFFF0000u);
        float r1 = p.y - __uint_as_float(u1 & 0xFFFF0000u);
        float r2 = p.z - __uint_as_float(u2 & 0xFFFF0000u);
        float r3 = p.w - __uint_as_float(u3 & 0xFFFF0000u);
        int slab = (b << 2) + (gi >> 6);
        size_t base = (size_t)slab * 16384 + (size_t)(lane >> 1) * 512
                    + (gi & 63) * 8 + ((lane & 1) << 2);
        *(uint2*)&Ph[base] = make_uint2(packhi(u1, u0), packhi(u3, u2));
        *(uint2*)&Pl[base] = make_uint2(packhi(__float_as_uint(r1), __float_as_uint(r0)),
                                        packhi(__float_as_uint(r3), __float_as_uint(r2)));
        if (lane == 0) { rmx[b * Nc + gi] = rm; rsm[b * Nc + gi] = rs; }
    }
}

// ---------------------------------------------------------------------------
// pv: out_rows = softmax_scale * (P @ H). A = P slabs (pre-split), B = H.
// SPLIT: epilogue writes x1 split slabs via LDS transpose (for next xf);
// else fp32 out (300 cols).
// ---------------------------------------------------------------------------
template<bool SPLIT>
__global__ void __launch_bounds__(256) pv_kernel(
    const ushort* __restrict__ Ph, const ushort* __restrict__ Pl,
    const ushort* __restrict__ Hh, const ushort* __restrict__ Hl,
    const float* __restrict__ rmx, const float* __restrict__ rsm,
    ushort* __restrict__ X1h, ushort* __restrict__ X1l,
    float* __restrict__ out, int OS) {
    __shared__ __align__(16) ushort smem[16384];
    __shared__ float sclS[256];
    __shared__ float mb[4], sb[4];
    const int tid = threadIdx.x;
    const int lane = tid & 63, wave = tid >> 6;
    const int wm = wave >> 1, wn = wave & 1;
    const int m = lane & 15, kch = lane >> 4;
    const int col0 = blockIdx.x * 64, row0 = blockIdx.y * 64;
    const int b = blockIdx.z;

    {   // flat-softmax merge: scale_i = exp(m_i - M)/S
        float mv = rmx[b * 256 + tid];
        float wmx = wredMax(mv);
        if (!lane) mb[wave] = wmx;
        __syncthreads();
        float M = fmaxf(fmaxf(mb[0], mb[1]), fmaxf(mb[2], mb[3]));
        float ex = expf(mv - M);
        float ws = wredSum(rsm[b * 256 + tid] * ex);
        if (!lane) sb[wave] = ws;
        __syncthreads();
        float S = sb[0] + sb[1] + sb[2] + sb[3];
        sclS[tid] = ex / S;
    }

    f32x4 acc[2][2];
#pragma unroll
    for (int i = 0; i < 2; i++)
#pragma unroll
        for (int j = 0; j < 2; j++)
#pragma unroll
            for (int e = 0; e < 4; e++) acc[i][j][e] = 0.f;

    const int slab = (b << 2) + blockIdx.y;
    gemm_core_async(smem,
                    (const char*)(Ph + (size_t)slab * 16384),
                    (const char*)(Pl + (size_t)slab * 16384),
                    (const char*)(Hh + (size_t)b * 81920),
                    (const char*)(Hl + (size_t)b * 81920),
                    320, col0, 256, acc);
    asm volatile("s_nop 7\ns_nop 7\ns_nop 7" ::);

    if constexpr (SPLIT) {
        // stash scaled acc into LDS [64 cols][66], then coalesced split write
        float* LF = (float*)smem;
#pragma unroll
        for (int fr = 0; fr < 2; fr++) {
            int rrel = wm * 32 + fr * 16 + (kch << 2);
#pragma unroll
            for (int fc = 0; fc < 2; fc++) {
                int crel = wn * 32 + fc * 16 + m;
#pragma unroll
                for (int e = 0; e < 4; e++)
                    LF[crel * 66 + rrel + e] = acc[fr][fc][e] * sclS[row0 + rrel + e];
            }
        }
        __syncthreads();
        for (int it = tid; it < 512; it += 256) {
            int cr = it >> 6, row = it & 63;
            float v[8];
#pragma unroll
            for (int e = 0; e < 8; e++) v[e] = LF[(cr * 8 + e) * 66 + row];
            unsigned hu[4], lu[4];
#pragma unroll
            for (int q = 0; q < 4; q++) {
                unsigned u0 = __float_as_uint(v[q * 2]);
                unsigned u1 = __float_as_uint(v[q * 2 + 1]);
                float r0 = v[q * 2] - __uint_as_float(u0 & 0xFFFF0000u);
                float r1 = v[q * 2 + 1] - __uint_as_float(u1 & 0xFFFF0000u);
                hu[q] = packhi(u1, u0);
                lu[q] = packhi(__float_as_uint(r1), __float_as_uint(r0));
            }
            size_t dst = (size_t)slab * 20480 + ((size_t)(col0 >> 3) + cr) * 512 + row * 8;
            *(uint4*)&X1h[dst] = make_uint4(hu[0], hu[1], hu[2], hu[3]);
            *(uint4*)&X1l[dst] = make_uint4(lu[0], lu[1], lu[2], lu[3]);
        }
    } else {
        float* ob = out + (size_t)b * 256 * OS;
#pragma unroll
        for (int fr = 0; fr < 2; fr++) {
            int rbase = row0 + wm * 32 + fr * 16 + (kch << 2);
#pragma unroll
            for (int fc = 0; fc < 2; fc++) {
                int col = col0 + wn * 32 + fc * 16 + m;
                if (col < OS) {
#pragma unroll
                    for (int e = 0; e < 4; e++)
                        ob[(size_t)(rbase + e) * OS + col] = acc[fr][fc][e] * sclS[rbase + e];
                }
            }
        }
    }
}

// ---------------------------------------------------------------------------
extern "C" void kernel_launch(void* const* d_in, const int* in_sizes, int n_in,
                              void* d_out, int out_size, void* d_ws, size_t ws_size,
                              hipStream_t stream) {
    const float* adj     = (const float*)d_in[0];
    const float* feature = (const float*)d_in[1];
    const float* W0      = (const float*)d_in[2];
    const float* b0      = (const float*)d_in[3];
    const float* W1      = (const float*)d_in[4];
    const float* b1      = (const float*)d_in[5];
    const float* A1      = (const float*)d_in[6];
    const float* ab1     = (const float*)d_in[7];
    const float* A2      = (const float*)d_in[8];
    const float* ab2     = (const float*)d_in[9];

    char* ws = (char*)d_ws;
    ushort* X1h   = (ushort*)(ws);                 // 2,621,440
    ushort* X1l   = (ushort*)(ws + 2621440);       // 2,621,440
    float*  si    = (float*)(ws + 5242880);        // 1,048,576
    float*  sjT   = (float*)(ws + 6291456);        // 1,048,576
    ushort* Ph    = (ushort*)(ws + 7340032);       // 2,097,152
    ushort* Pl    = (ushort*)(ws + 9437184);       // 2,097,152
    float*  rmx   = (float*)(ws + 11534336);       // 16,384
    float*  rsm   = (float*)(ws + 11550720);       // 16,384
    float*  bias0 = (float*)(ws + 11567104);       // 1,792
    float*  bias1 = (float*)(ws + 11568896);       // 1,792
    ushort* F0h   = (ushort*)(ws + 11570688);      // 688,128
    ushort* F0l   = (ushort*)(ws + 12258816);      // 688,128
    ushort* F1h   = (ushort*)(ws + 12946944);      // 286,720
    ushort* F1l   = (ushort*)(ws + 13233664);      // 286,720
    ushort* Hh    = (ushort*)(ws + 13520384);      // 2,621,440
    ushort* Hl    = (ushort*)(ws + 16141824);      // 2,621,440
    ushort* Xh    = (ushort*)(ws + 18763264);      // 6,291,456
    ushort* Xl    = (ushort*)(ws + 25054720);      // 6,291,456  end 31,346,176
    float* outp   = (float*)d_out;

    convert_all<<<2254, 256, 0, stream>>>(W0, b0, W1, b1, A1, ab1, feature,
                                          F0h, F0l, F1h, F1l, bias0, bias1, Xh, Xl);

    for (int L = 0; L < 2; L++) {
        const ushort* Ah = L ? X1h : Xh;
        const ushort* Al = L ? X1l : Xl;
        const ushort* Fh = L ? F1h : F0h;
        const ushort* Fl = L ? F1l : F0l;
        const float* bf = L ? bias1 : bias0;
        int Kp = L ? 320 : 768;

        xf_kernel<<<dim3(7, 64), 256, 0, stream>>>(
            Ah, Al, Kp, Fh, Fl, bf, Hh, Hl, si, sjT);
        scores_kernel<<<dim3(16, 32), 256, 0, stream>>>(
            si, sjT, adj, A2, ab2, Ph, Pl, rmx, rsm);
        if (L == 0)
            pv_kernel<true><<<dim3(5, 4, 16), 256, 0, stream>>>(
                Ph, Pl, Hh, Hl, rmx, rsm, X1h, X1l, nullptr, 0);
        else
            pv_kernel<false><<<dim3(5, 4, 16), 256, 0, stream>>>(
                Ph, Pl, Hh, Hl, rmx, rsm, nullptr, nullptr, outp, 300);
    }
}